// Round 9
// baseline (450.021 us; speedup 1.0000x reference)
//
#include <hip/hip_runtime.h>

// ---------------- problem constants (match reference setup_inputs) ----------
#define NVOX 12000
#define NPTS 32
#define CIN  5
#define C1   64     // VFE1 out
#define C2   128    // VFE2 out
#define GD   16
#define GH   128
#define GW   128
#define SP   (GD*GH*GW)          // 262144
static constexpr float EPSBN = 1e-5f;

typedef unsigned short ushortT;
typedef __attribute__((ext_vector_type(8))) short bf16x8;
typedef __attribute__((ext_vector_type(4))) float f32x4;

__device__ inline ushortT f2bf(float f) {
    unsigned int x = __float_as_uint(f);
    unsigned int r = (x + 0x7FFFu + ((x >> 16) & 1u)) >> 16;   // RNE
    return (ushortT)r;
}
__device__ inline float bf2f(ushortT u) { return __uint_as_float(((unsigned int)u) << 16); }

// padded spatial dims
#define P1D 18
#define P1H 130
#define P1W 130
#define PSP1 (P1D*P1H*P1W)       // 304200
#define P2D 10
#define P2H 66
#define P2W 66
#define PSP2 (P2D*P2H*P2W)       // 43560
#define P3D 6
#define P3H 34
#define P3W 34
#define PSP3 (P3D*P3H*P3W)       // 6936

// NOTE: biases (b1,b2,cb1..3) are mathematically no-ops: every linear/conv is
// immediately followed by training-mode BN which subtracts the per-channel
// mean; a per-channel constant shifts mean but not variance. Skipped.

// ---------------- prep: weight convert + vfe1 stats + scatter (fused) -------
// wb layout: [cob][cig][tap][cogT][lane][8], CO_T=64 for all convs
__device__ inline void conv_w_one(const float* cw, ushortT* wb, int CI_, int CO_T_,
                                  int NCIG_, int e) {
    int NCOG_T_ = CO_T_ >> 4;
    int j = e & 7, lane = (e >> 3) & 63, r = e >> 9;
    int f = r % NCOG_T_; r /= NCOG_T_;
    int tap = r % 27;    r /= 27;
    int cig = r % NCIG_; int cob = r / NCIG_;
    int co = cob*CO_T_ + f*16 + (lane & 15);
    int ci = cig*32 + (lane >> 4)*8 + j;
    wb[e] = f2bf(cw[((size_t)co*CI_ + ci)*27 + tap]);
}

__global__ void prep(const float* __restrict__ x, const float* __restrict__ w1,
                     float* __restrict__ s1sum,
                     const float* __restrict__ cw1, const float* __restrict__ cw2,
                     const float* __restrict__ cw3, ushortT* __restrict__ wb1,
                     ushortT* __restrict__ wb2, ushortT* __restrict__ wb3,
                     const int* __restrict__ coords, int* __restrict__ winner) {
    __shared__ float s_w[CIN*C1];
    __shared__ float s_red[2][4][C1];
    const int blk = blockIdx.x;
    const int t = threadIdx.x;
    if (blk < 960) {
        for (int i = t; i < CIN*C1; i += 256) s_w[i] = w1[i];
        __syncthreads();
        int ch = t & 63, rr = t >> 6;
        float sum = 0.f, sq = 0.f;
        const int NROWS = NVOX * NPTS;
        for (int row = blk*4 + rr; row < NROWS; row += 960*4) {
            const float* xr = x + row*CIN;
            float y = 0.f;
            #pragma unroll
            for (int c = 0; c < CIN; ++c) y += xr[c] * s_w[c*C1 + ch];
            sum += y; sq += y*y;
        }
        s_red[0][rr][ch] = sum; s_red[1][rr][ch] = sq;
        __syncthreads();
        if (rr == 0) {
            sum = s_red[0][0][ch]+s_red[0][1][ch]+s_red[0][2][ch]+s_red[0][3][ch];
            sq  = s_red[1][0][ch]+s_red[1][1][ch]+s_red[1][2][ch]+s_red[1][3][ch];
            atomicAdd(&s1sum[ch], sum);
            atomicAdd(&s1sum[C1+ch], sq);
        }
    } else if (blk < 1984) {
        const int N1 = 442368, N2 = 884736, N3 = 1769472;
        const int total = N1+N2+N3;
        for (int e0 = (blk-960)*256 + t; e0 < total; e0 += 1024*256) {
            if (e0 < N1)         conv_w_one(cw1, wb1, 128, 64, 4, e0);
            else if (e0 < N1+N2) conv_w_one(cw2, wb2, 128, 64, 4, e0-N1);
            else                 conv_w_one(cw3, wb3, 256, 64, 8, e0-N1-N2);
        }
    } else {
        int v = (blk-1984)*256 + t;
        if (v < NVOX) {
            int d = coords[v*3+0], h = coords[v*3+1], w = coords[v*3+2];
            atomicMax(&winner[(d*GH + h)*GW + w], v);
        }
    }
}

// ---------------- VFE1 apply: inline BN finalize ---------------------------
__global__ void vfe1_apply(const float* __restrict__ x, const float* __restrict__ w1,
                           const float* __restrict__ sums, const float* __restrict__ g,
                           const float* __restrict__ be, float* __restrict__ f1) {
    __shared__ float s_w[CIN*C1];
    __shared__ float s_x[NPTS*CIN];
    int v = blockIdx.x, t = threadIdx.x; // 64 threads
    for (int i = t; i < CIN*C1; i += 64) s_w[i] = w1[i];
    for (int i = t; i < NPTS*CIN; i += 64) s_x[i] = x[v*NPTS*CIN + i];
    const float invN = 1.f/(NVOX*NPTS);
    float mean = sums[t]*invN;
    float var  = sums[C1+t]*invN - mean*mean;
    float sc = g[t]*rsqrtf(var + EPSBN);
    float sh = be[t] - mean*sc;
    __syncthreads();
    float m = 0.f;
    for (int p = 0; p < NPTS; ++p) {
        float y = 0.f;
        #pragma unroll
        for (int c = 0; c < CIN; ++c) y += s_x[p*CIN+c]*s_w[c*C1+t];
        m = fmaxf(m, y*sc + sh);
    }
    f1[v*C1 + t] = m;
}

// ---------------- VFE2 linear (transposed padded weights, float4 reads) ----
__global__ void vfe2_linear(const float* __restrict__ f1, const float* __restrict__ w2,
                            float* __restrict__ y2, float* __restrict__ sums) {
    __shared__ float s_w[C2][68];
    __shared__ float s_f[16*C1];
    int t = threadIdx.x; // 128
    for (int i = t; i < C1*C2; i += 128) {
        int c = i >> 7, o = i & 127;
        s_w[o][c] = w2[i];
    }
    int v0 = blockIdx.x*16;
    for (int i = t; i < 16*C1; i += 128) s_f[i] = f1[v0*C1 + i];
    __syncthreads();
    float sum = 0.f, sq = 0.f;
    for (int vl = 0; vl < 16; ++vl) {
        float y = 0.f;
        #pragma unroll
        for (int c4 = 0; c4 < C1; c4 += 4) {
            float4 f = *(const float4*)&s_f[vl*C1 + c4];
            float4 w = *(const float4*)&s_w[t][c4];
            y += f.x*w.x + f.y*w.y + f.z*w.z + f.w*w.w;
        }
        y2[(v0+vl)*C2 + t] = y;
        sum += y; sq += y*y;
    }
    atomicAdd(&sums[t], sum);
    atomicAdd(&sums[C2+t], sq);
}

// VFE2 apply -> bf16, inline finalize
__global__ void vfe2_apply_bf16(const float* __restrict__ y2, const float* __restrict__ sums,
                                const float* __restrict__ g, const float* __restrict__ be,
                                ushortT* __restrict__ f2b) {
    __shared__ float s_sc[C2], s_sh[C2];
    int t = threadIdx.x;
    if (t < C2) {
        const float invN = 1.f/NVOX;
        float mean = sums[t]*invN;
        float var  = sums[C2+t]*invN - mean*mean;
        float sc = g[t]*rsqrtf(var + EPSBN);
        s_sc[t] = sc; s_sh[t] = be[t] - mean*sc;
    }
    __syncthreads();
    int i = blockIdx.x*256 + t;
    if (i >= NVOX*C2/4) return;
    const float4 v = *(const float4*)(y2 + (size_t)i*4);
    int c0 = (i*4) & (C2-1);
    ushort4 o;
    o.x = f2bf(fmaxf(0.f, v.x*s_sc[c0+0]+s_sh[c0+0]));
    o.y = f2bf(fmaxf(0.f, v.y*s_sc[c0+1]+s_sh[c0+1]));
    o.z = f2bf(fmaxf(0.f, v.z*s_sc[c0+2]+s_sh[c0+2]));
    o.w = f2bf(fmaxf(0.f, v.w*s_sc[c0+3]+s_sh[c0+3]));
    *(ushort4*)(f2b + (size_t)i*4) = o;
}

// ---------------- build padded dense grid, cig-major -----------------------
__global__ void build_grid_pad(const int* __restrict__ winner,
                               const ushortT* __restrict__ f2b,
                               ushortT* __restrict__ grid) {
    const int total = 4*PSP1*4;   // cig x pos x 4 chunks
    for (int e = blockIdx.x*256 + threadIdx.x; e < total; e += gridDim.x*256) {
        int sub = e & 3;
        int r = e >> 2;             // cig*PSP1 + pos
        int cig = r / PSP1;
        int pos = r - cig*PSP1;
        int pz = pos / (P1H*P1W);
        int rr = pos - pz*(P1H*P1W);
        int py = rr / P1W;
        int px = rr - py*P1W;
        unsigned dz = pz-1, dy = py-1, dx = px-1;
        int4 v = {0,0,0,0};
        if (dz < GD && dy < GH && dx < GW) {
            int wn = winner[(dz*GH + dy)*GW + dx];
            if (wn >= 0)
                v = *(const int4*)(f2b + (size_t)wn*C2 + cig*32 + sub*8);
        }
        *(int4*)(grid + (size_t)e*8) = v;
    }
}

// ---------------- MFMA implicit-GEMM conv3d, stride 2, k=3 ----------------
// 256 thr = 4 waves (2 co x 2 sp); wave tile 32co x 32sp, block 64co x 64sp.
// BARRIER-FREE tap loop: A (weights) live in VGPRs, loaded from L2-resident wb
// in 9-tap double-buffered chunks (aA/aB, fully static). Per tap: 2 ds_read_b128
// B-frags feed 4 MFMAs. Only 2 barriers per cig (around s_in staging).
// s_in rows: 40 ushorts (80B) -> bank starts cycle 8 values; chunk-XOR swizzle.
template<int CI, int CO, int PD, int PH, int PW, int DO, int HO, int WO,
         int OPD, int OPH, int OPW, int NSLICE, bool BNSTAGE, bool ATOMIC>
__global__ __launch_bounds__(256, 2) void conv3d_mfma(
        const ushortT* __restrict__ in_p, const ushortT* __restrict__ wb,
        void* __restrict__ outp, float* __restrict__ sums_out,
        const float* __restrict__ bn_sums, const float* __restrict__ bn_g,
        const float* __restrict__ bn_be, float bn_invN) {
    constexpr int CO_T   = 64;
    constexpr int NCIG   = CI/32;
    constexpr int NCOG_T = CO_T/16;       // 4
    constexpr int TAPU   = NCOG_T*512;    // 2048 ushorts per tap tile
    constexpr int CPB    = NCIG/NSLICE;
    __shared__ ushortT s_in[867*40];      // 69.4 KB
    __shared__ float   s_sc[BNSTAGE ? CI : 1];
    __shared__ float   s_sh[BNSTAGE ? CI : 1];

    constexpr int nbx = WO/8, nby = HO/8;
    int b = blockIdx.x;
    const int bx = b % nbx; b /= nbx;
    const int by = b % nby; b /= nby;
    const int bz = b % DO;  b /= DO;
    const int cob   = b % (CO/CO_T);
    const int slice = b / (CO/CO_T);
    const int co0 = cob*CO_T;
    const int oy0 = by*8, ox0 = bx*8;
    const int t = threadIdx.x;
    const int lane = t & 63, wid = t >> 6;
    const int lr = lane & 15, lq = lane >> 4;
    const int wm = wid & 1, wn = wid >> 1;

    if constexpr (BNSTAGE) {
        for (int c = t; c < CI; c += 256) {
            float mean = bn_sums[c]*bn_invN;
            float var  = bn_sums[CI+c]*bn_invN - mean*mean;
            float sc = bn_g[c]*rsqrtf(var + EPSBN);
            s_sc[c] = sc; s_sh[c] = bn_be[c] - mean*sc;
        }
        __syncthreads();
    }

    // B-frag spatial bases: bp = position in 17x17 plane (z=0), always even
    int bp[2], bq[2];
    #pragma unroll
    for (int fn = 0; fn < 2; ++fn) {
        int n = wn*32 + fn*16 + lr;
        int oy = n >> 3, ox = n & 7;
        bp[fn] = 34*oy + 2*ox;
        bq[fn] = bp[fn] >> 1;
    }

    f32x4 acc[2][2];
    #pragma unroll
    for (int i = 0; i < 2; ++i)
        #pragma unroll
        for (int j = 0; j < 2; ++j) acc[i][j] = (f32x4){0.f,0.f,0.f,0.f};

    bf16x8 aA[9][2], aB[9][2];

#define A_ISSUE(dst, ch) { \
    _Pragma("unroll") for (int tp = 0; tp < 9; ++tp) \
    _Pragma("unroll") for (int fm = 0; fm < 2; ++fm) \
        dst[tp][fm] = *(const bf16x8*)(wcig + ((ch)*9 + tp)*TAPU + fm*512); }

#define CCHUNK(src, ch) { \
    _Pragma("unroll") for (int tp = 0; tp < 9; ++tp) { \
        const int n_ = (ch)*9 + tp; \
        const int kz_ = n_/9, ky_ = (n_/3)%3, kx_ = n_%3; \
        const int toff_ = kz_*289 + ky_*17 + kx_; \
        const int th_ = toff_ >> 1; \
        bf16x8 b0 = *(const bf16x8*)(s_in + (bp[0]+toff_)*40 + ((lq ^ ((bq[0]+th_)&3))<<3)); \
        bf16x8 b1 = *(const bf16x8*)(s_in + (bp[1]+toff_)*40 + ((lq ^ ((bq[1]+th_)&3))<<3)); \
        acc[0][0] = __builtin_amdgcn_mfma_f32_16x16x32_bf16(src[tp][0], b0, acc[0][0],0,0,0); \
        acc[0][1] = __builtin_amdgcn_mfma_f32_16x16x32_bf16(src[tp][0], b1, acc[0][1],0,0,0); \
        acc[1][0] = __builtin_amdgcn_mfma_f32_16x16x32_bf16(src[tp][1], b0, acc[1][0],0,0,0); \
        acc[1][1] = __builtin_amdgcn_mfma_f32_16x16x32_bf16(src[tp][1], b1, acc[1][1],0,0,0); } }

    for (int cig = slice*CPB; cig < slice*CPB + CPB; ++cig) {
        const ushortT* wcig = wb + ((size_t)(cob*NCIG + cig)*27)*TAPU
                                 + (wm*2)*512 + (lane << 3);
        A_ISSUE(aA, 0);                 // chunk-0 weights; latency hides in staging
        float scr[8], shr[8];
        if constexpr (BNSTAGE) {
            int ch0 = cig*32 + (t&3)*8;
            #pragma unroll
            for (int jj = 0; jj < 8; ++jj) { scr[jj] = s_sc[ch0+jj]; shr[jj] = s_sh[ch0+jj]; }
        }
        __syncthreads();   // all waves done reading s_in from previous cig
        // ---- stage input tile: coalesced reads, swizzled LDS writes ----
        const ushortT* icig = in_p + (size_t)cig*PD*PH*PW*32;
        for (int c = t; c < 3468; c += 256) {
            int pos = c >> 2, sub = c & 3;
            int zz = pos/289, rr = pos - zz*289, yy = rr/17, xx = rr - yy*17;
            int pz = 2*bz + zz, py = 2*oy0 + yy, px = 2*ox0 + xx;
            int4 v = *(const int4*)(icig + ((size_t)(pz*PH + py)*PW + px)*32 + sub*8);
            if constexpr (BNSTAGE) {
                // BN+relu only on interior; pads must remain ZERO
                bool inb = ((unsigned)(pz-1) < (unsigned)(PD-2)) &&
                           ((unsigned)(py-1) < (unsigned)(PH-2)) &&
                           ((unsigned)(px-1) < (unsigned)(PW-2));
                if (inb) {
                    ushortT* u = (ushortT*)&v;
                    #pragma unroll
                    for (int jj = 0; jj < 8; ++jj)
                        u[jj] = f2bf(fmaxf(0.f, bf2f(u[jj])*scr[jj] + shr[jj]));
                } else {
                    v = (int4){0,0,0,0};
                }
            }
            int col = sub ^ ((pos >> 1) & 3);
            *(int4*)(s_in + pos*40 + (col<<3)) = v;
        }
        __syncthreads();
        // ---- barrier-free tap loop: 27 taps = 3 chunks of 9 ----
        A_ISSUE(aB, 1);
        CCHUNK(aA, 0);
        A_ISSUE(aA, 2);
        CCHUNK(aB, 1);
        CCHUNK(aA, 2);
    }
#undef A_ISSUE
#undef CCHUNK

    if constexpr (!ATOMIC) {
        // bf16 out in padded cig-major layout for next conv's staging
        ushortT* out = (ushortT*)outp;
        #pragma unroll
        for (int fm = 0; fm < 2; ++fm)
        #pragma unroll
        for (int fn = 0; fn < 2; ++fn) {
            int n = wn*32 + fn*16 + lr;
            int oy = n >> 3, ox = n & 7;
            int c_ = co0 + wm*32 + fm*16 + lq*4;
            size_t pa = (((size_t)(c_ >> 5)*OPD + bz+1)*OPH + (oy0+oy+1))*OPW + (ox0+ox+1);
            ushort4 o;
            o.x = f2bf(acc[fm][fn][0]); o.y = f2bf(acc[fm][fn][1]);
            o.z = f2bf(acc[fm][fn][2]); o.w = f2bf(acc[fm][fn][3]);
            *(ushort4*)(out + pa*32 + (c_ & 31)) = o;
        }
        // fused BN stats on fp32 accumulators
        #pragma unroll
        for (int fm = 0; fm < 2; ++fm) {
            float s[4], q[4];
            #pragma unroll
            for (int r = 0; r < 4; ++r) {
                float a0 = acc[fm][0][r], a1 = acc[fm][1][r];
                s[r] = a0 + a1; q[r] = a0*a0 + a1*a1;
                #pragma unroll
                for (int m = 1; m < 16; m <<= 1) {
                    s[r] += __shfl_xor(s[r], m, 64);
                    q[r] += __shfl_xor(q[r], m, 64);
                }
            }
            if (lr == 0) {
                int c_ = co0 + wm*32 + fm*16 + lq*4;
                #pragma unroll
                for (int r = 0; r < 4; ++r) {
                    atomicAdd(&sums_out[c_+r], s[r]);
                    atomicAdd(&sums_out[CO + c_+r], q[r]);
                }
            }
        }
    } else {
        float* out = (float*)outp;
        #pragma unroll
        for (int fm = 0; fm < 2; ++fm)
        #pragma unroll
        for (int fn = 0; fn < 2; ++fn) {
            int n = wn*32 + fn*16 + lr;
            int oy = n >> 3, ox = n & 7;
            int c_ = co0 + wm*32 + fm*16 + lq*4;
            #pragma unroll
            for (int r = 0; r < 4; ++r)
                atomicAdd(&out[((size_t)(c_+r)*DO + bz)*(HO*WO) + (oy0+oy)*WO + ox0+ox],
                          acc[fm][fn][r]);
        }
    }
}

// ---------------- BN for channel-major fp32 (final output) -----------------
template<int SPL>
__global__ void bn_stats_cmajor(const float* __restrict__ y, const float* __restrict__ g,
                                const float* __restrict__ be, float* __restrict__ ss, int C) {
    __shared__ float s_red[2][256];
    int c = blockIdx.x;
    const float* p = y + (size_t)c*SPL;
    float sum = 0.f, sq = 0.f;
    for (int i = threadIdx.x; i < SPL; i += 256) { float v = p[i]; sum += v; sq += v*v; }
    s_red[0][threadIdx.x] = sum; s_red[1][threadIdx.x] = sq;
    __syncthreads();
    for (int s = 128; s > 0; s >>= 1) {
        if (threadIdx.x < s) {
            s_red[0][threadIdx.x] += s_red[0][threadIdx.x+s];
            s_red[1][threadIdx.x] += s_red[1][threadIdx.x+s];
        }
        __syncthreads();
    }
    if (threadIdx.x == 0) {
        float invN = 1.f/(float)SPL;
        float mean = s_red[0][0]*invN;
        float var  = s_red[1][0]*invN - mean*mean;
        float sc = g[c]*rsqrtf(var + EPSBN);
        ss[c] = sc; ss[C+c] = be[c] - mean*sc;
    }
}

template<int LOGSPL>
__global__ void bn_apply_cmajor(float* __restrict__ y, const float* __restrict__ ss,
                                int C, int total) {
    for (int i = blockIdx.x*blockDim.x + threadIdx.x; i < total; i += gridDim.x*blockDim.x) {
        int c = i >> LOGSPL;
        y[i] = fmaxf(0.f, y[i]*ss[c] + ss[C+c]);
    }
}

// ---------------- host launcher --------------------------------------------
extern "C" void kernel_launch(void* const* d_in, const int* in_sizes, int n_in,
                              void* d_out, int out_size, void* d_ws, size_t ws_size,
                              hipStream_t stream) {
    const float* x      = (const float*)d_in[0];
    const int*   coords = (const int*)  d_in[1];
    const float* w1  = (const float*)d_in[5];
    const float* g1  = (const float*)d_in[7];
    const float* be1 = (const float*)d_in[8];
    const float* w2  = (const float*)d_in[9];
    const float* g2  = (const float*)d_in[11];
    const float* be2 = (const float*)d_in[12];
    const float* cw1 = (const float*)d_in[13];
    const float* cg1 = (const float*)d_in[15];
    const float* cbe1= (const float*)d_in[16];
    const float* cw2 = (const float*)d_in[17];
    const float* cg2 = (const float*)d_in[19];
    const float* cbe2= (const float*)d_in[20];
    const float* cw3 = (const float*)d_in[21];
    const float* cg3 = (const float*)d_in[23];
    const float* cbe3= (const float*)d_in[24];
    float* out = (float*)d_out;

    // ---- workspace layout ----
    float*   ws     = (float*)d_ws;
    float*   stats  = ws;                                    // 4096 f32
    int*     winner = (int*)(ws + 4096);                     // SP ints
    float*   f1     = (float*)(winner + SP);                 // 12000*64 f32
    float*   y2     = f1 + (size_t)NVOX*C1;                  // 12000*128 f32
    ushortT* f2b    = (ushortT*)(y2 + (size_t)NVOX*C2);      // 12000*128 bf16
    ushortT* gridp  = f2b + (size_t)NVOX*C2;                 // 4*PSP1*32
    ushortT* c1o    = gridp + (size_t)4*PSP1*32;             // 4*PSP2*32
    ushortT* c2o    = c1o + (size_t)4*PSP2*32;               // 8*PSP3*32
    ushortT* wb1    = c2o + (size_t)8*PSP3*32;               // 442368
    ushortT* wb2    = wb1 + 442368;                          // 884736
    ushortT* wb3    = wb2 + 884736;                          // 1769472

    float* s1sum = stats;          // 128 (64 sum + 64 sq)
    float* s2sum = stats + 128;    // 256
    float* c1sum = stats + 384;    // 256
    float* c2sum = stats + 640;    // 512
    float* ss3   = stats + 1152;   // 512

    hipMemsetAsync(stats, 0, 4096*sizeof(float), stream);
    hipMemsetAsync(winner, 0xFF, SP*sizeof(int), stream);
    hipMemsetAsync(c1o, 0, (size_t)4*PSP2*32*2, stream);     // zero pads for conv2 stage
    hipMemsetAsync(c2o, 0, (size_t)8*PSP3*32*2, stream);     // zero pads for conv3 stage
    hipMemsetAsync(d_out, 0, (size_t)out_size*sizeof(float), stream);

    // prep: vfe1 stats (960) + weight convert (1024) + scatter (47)
    prep<<<2031, 256, 0, stream>>>(x, w1, s1sum, cw1, cw2, cw3, wb1, wb2, wb3,
                                   coords, winner);

    vfe1_apply<<<NVOX, 64, 0, stream>>>(x, w1, s1sum, g1, be1, f1);
    vfe2_linear<<<NVOX/16, 128, 0, stream>>>(f1, w2, y2, s2sum);
    vfe2_apply_bf16<<<NVOX*C2/4/256, 256, 0, stream>>>(y2, s2sum, g2, be2, f2b);

    // dense padded grid (pads written as zeros; scatter absorbed here)
    build_grid_pad<<<4096, 256, 0, stream>>>(winner, f2b, gridp);

    // conv1: 128->128, grid(18,130,130) -> c1o padded(10,66,66); 1024 blocks
    conv3d_mfma<128,128, P1D,P1H,P1W, 8,64,64, P2D,P2H,P2W, 1, false, false>
        <<<8*8*8*2, 256, 0, stream>>>(gridp, wb1, c1o, c1sum,
                                      nullptr, nullptr, nullptr, 0.f);
    // conv2: 128->256, c1o(10,66,66) -> c2o padded(6,34,34); BN1 on stage; 256 blocks
    conv3d_mfma<128,256, P2D,P2H,P2W, 4,32,32, P3D,P3H,P3W, 1, true, false>
        <<<4*4*4*4, 256, 0, stream>>>(c1o, wb2, c2o, c2sum,
                                      c1sum, cg1, cbe1, 1.f/32768.f);
    // conv3: 256->256, c2o(6,34,34) -> d_out cmajor fp32; BN2 on stage; split-K x8
    conv3d_mfma<256,256, P3D,P3H,P3W, 2,16,16, 1,1,1, 8, true, true>
        <<<2*2*2*4*8, 256, 0, stream>>>(c2o, wb3, (void*)out, nullptr,
                                        c2sum, cg2, cbe2, 1.f/4096.f);

    bn_stats_cmajor<2*16*16><<<256, 256, 0, stream>>>(out, cg3, cbe3, ss3, 256);
    bn_apply_cmajor<9><<<512, 256, 0, stream>>>(out, ss3, 256, 131072);
}

// Round 10
// 281.781 us; speedup vs baseline: 1.5971x; 1.5971x over previous
//
#include <hip/hip_runtime.h>

// ---------------- problem constants ----------------------------------------
#define NVOX 12000
#define NPTS 32
#define CIN  5
#define C1   64
#define C2   128
#define GD   16
#define GH   128
#define GW   128
#define SP   (GD*GH*GW)
static constexpr float EPSBN = 1e-5f;

typedef unsigned short ushortT;
typedef __attribute__((ext_vector_type(8))) short bf16x8;
typedef __attribute__((ext_vector_type(4))) float f32x4;

__device__ inline ushortT f2bf(float f) {
    unsigned int x = __float_as_uint(f);
    unsigned int r = (x + 0x7FFFu + ((x >> 16) & 1u)) >> 16;   // RNE
    return (ushortT)r;
}
__device__ inline float bf2f(ushortT u) { return __uint_as_float(((unsigned int)u) << 16); }

__device__ inline void gload16(const ushortT* g, ushortT* l) {
    __builtin_amdgcn_global_load_lds(
        (const __attribute__((address_space(1))) unsigned int*)g,
        (__attribute__((address_space(3))) unsigned int*)l, 16, 0, 0);
}

// padded spatial dims (channels-LAST layouts: [pos][C])
#define P1D 18
#define P1H 130
#define P1W 130
#define PSP1 (P1D*P1H*P1W)
#define P2D 10
#define P2H 66
#define P2W 66
#define PSP2 (P2D*P2H*P2W)
#define P3D 6
#define P3H 34
#define P3W 34
#define PSP3 (P3D*P3H*P3W)

// NOTE: biases are exact no-ops under training-mode BN (mean-subtracted).

// ---------------- prep: weight convert + vfe1 stats + scatter ---------------
// wb: per phase a linear tile of TCO*16 chunks (16B); chunk p=(col,cp):
// content = w[cob*TCO+col][ci=(cp^(col&7))*8+j [+128 for CI=256 odd phase]]
__device__ inline void conv_w_one(const float* cw, ushortT* wb, int CI_, int TCO_,
                                  int NS_, int e) {
    int j = e & 7;
    int rest = e >> 3;
    int CHN = TCO_*16;
    int p = rest % CHN; int r = rest / CHN;
    int s = r % NS_;    int cob = r / NS_;
    int col = p >> 4, cp = p & 15;
    int cl = cp ^ (col & 7);
    int tap = (CI_==256) ? (s>>1) : s;
    int cib = (CI_==256) ? ((s&1)*128) : 0;
    int co = cob*TCO_ + col;
    int ci = cib + cl*8 + j;
    wb[e] = f2bf(cw[((size_t)co*CI_ + ci)*27 + tap]);
}

__global__ void prep(const float* __restrict__ x, const float* __restrict__ w1,
                     float* __restrict__ s1sum,
                     const float* __restrict__ cw1, const float* __restrict__ cw2,
                     const float* __restrict__ cw3, ushortT* __restrict__ wb1,
                     ushortT* __restrict__ wb2, ushortT* __restrict__ wb3,
                     const int* __restrict__ coords, int* __restrict__ winner) {
    __shared__ float s_w[CIN*C1];
    __shared__ float s_red[2][4][C1];
    const int blk = blockIdx.x;
    const int t = threadIdx.x;
    if (blk < 960) {
        for (int i = t; i < CIN*C1; i += 256) s_w[i] = w1[i];
        __syncthreads();
        int ch = t & 63, rr = t >> 6;
        float sum = 0.f, sq = 0.f;
        const int NROWS = NVOX * NPTS;
        for (int row = blk*4 + rr; row < NROWS; row += 960*4) {
            const float* xr = x + row*CIN;
            float y = 0.f;
            #pragma unroll
            for (int c = 0; c < CIN; ++c) y += xr[c] * s_w[c*C1 + ch];
            sum += y; sq += y*y;
        }
        s_red[0][rr][ch] = sum; s_red[1][rr][ch] = sq;
        __syncthreads();
        if (rr == 0) {
            sum = s_red[0][0][ch]+s_red[0][1][ch]+s_red[0][2][ch]+s_red[0][3][ch];
            sq  = s_red[1][0][ch]+s_red[1][1][ch]+s_red[1][2][ch]+s_red[1][3][ch];
            atomicAdd(&s1sum[ch], sum);
            atomicAdd(&s1sum[C1+ch], sq);
        }
    } else if (blk < 1984) {
        const int N1 = 442368, N2 = 884736, N3 = 1769472;
        const int total = N1+N2+N3;
        for (int e0 = (blk-960)*256 + t; e0 < total; e0 += 1024*256) {
            if (e0 < N1)         conv_w_one(cw1, wb1, 128, 128, 27, e0);
            else if (e0 < N1+N2) conv_w_one(cw2, wb2, 128, 64,  27, e0-N1);
            else                 conv_w_one(cw3, wb3, 256, 64,  54, e0-N1-N2);
        }
    } else {
        int v = (blk-1984)*256 + t;
        if (v < NVOX) {
            int d = coords[v*3+0], h = coords[v*3+1], w = coords[v*3+2];
            atomicMax(&winner[(d*GH + h)*GW + w], v);
        }
    }
}

// ---------------- VFE1 apply ------------------------------------------------
__global__ void vfe1_apply(const float* __restrict__ x, const float* __restrict__ w1,
                           const float* __restrict__ sums, const float* __restrict__ g,
                           const float* __restrict__ be, float* __restrict__ f1) {
    __shared__ float s_w[CIN*C1];
    __shared__ float s_x[NPTS*CIN];
    int v = blockIdx.x, t = threadIdx.x; // 64 threads
    for (int i = t; i < CIN*C1; i += 64) s_w[i] = w1[i];
    for (int i = t; i < NPTS*CIN; i += 64) s_x[i] = x[v*NPTS*CIN + i];
    const float invN = 1.f/(NVOX*NPTS);
    float mean = sums[t]*invN;
    float var  = sums[C1+t]*invN - mean*mean;
    float sc = g[t]*rsqrtf(var + EPSBN);
    float sh = be[t] - mean*sc;
    __syncthreads();
    float m = 0.f;
    for (int p = 0; p < NPTS; ++p) {
        float y = 0.f;
        #pragma unroll
        for (int c = 0; c < CIN; ++c) y += s_x[p*CIN+c]*s_w[c*C1+t];
        m = fmaxf(m, y*sc + sh);
    }
    f1[v*C1 + t] = m;
}

// ---------------- VFE2 linear ----------------------------------------------
__global__ void vfe2_linear(const float* __restrict__ f1, const float* __restrict__ w2,
                            float* __restrict__ y2, float* __restrict__ sums) {
    __shared__ float s_w[C2][68];
    __shared__ float s_f[16*C1];
    int t = threadIdx.x; // 128
    for (int i = t; i < C1*C2; i += 128) {
        int c = i >> 7, o = i & 127;
        s_w[o][c] = w2[i];
    }
    int v0 = blockIdx.x*16;
    for (int i = t; i < 16*C1; i += 128) s_f[i] = f1[v0*C1 + i];
    __syncthreads();
    float sum = 0.f, sq = 0.f;
    for (int vl = 0; vl < 16; ++vl) {
        float y = 0.f;
        #pragma unroll
        for (int c4 = 0; c4 < C1; c4 += 4) {
            float4 f = *(const float4*)&s_f[vl*C1 + c4];
            float4 w = *(const float4*)&s_w[t][c4];
            y += f.x*w.x + f.y*w.y + f.z*w.z + f.w*w.w;
        }
        y2[(v0+vl)*C2 + t] = y;
        sum += y; sq += y*y;
    }
    atomicAdd(&sums[t], sum);
    atomicAdd(&sums[C2+t], sq);
}

__global__ void vfe2_apply_bf16(const float* __restrict__ y2, const float* __restrict__ sums,
                                const float* __restrict__ g, const float* __restrict__ be,
                                ushortT* __restrict__ f2b) {
    __shared__ float s_sc[C2], s_sh[C2];
    int t = threadIdx.x;
    if (t < C2) {
        const float invN = 1.f/NVOX;
        float mean = sums[t]*invN;
        float var  = sums[C2+t]*invN - mean*mean;
        float sc = g[t]*rsqrtf(var + EPSBN);
        s_sc[t] = sc; s_sh[t] = be[t] - mean*sc;
    }
    __syncthreads();
    int i = blockIdx.x*256 + t;
    if (i >= NVOX*C2/4) return;
    const float4 v = *(const float4*)(y2 + (size_t)i*4);
    int c0 = (i*4) & (C2-1);
    ushort4 o;
    o.x = f2bf(fmaxf(0.f, v.x*s_sc[c0+0]+s_sh[c0+0]));
    o.y = f2bf(fmaxf(0.f, v.y*s_sc[c0+1]+s_sh[c0+1]));
    o.z = f2bf(fmaxf(0.f, v.z*s_sc[c0+2]+s_sh[c0+2]));
    o.w = f2bf(fmaxf(0.f, v.w*s_sc[c0+3]+s_sh[c0+3]));
    *(ushort4*)(f2b + (size_t)i*4) = o;
}

// ---------------- build padded dense grid, channels-last [pos][128] --------
__global__ void build_grid_cl(const int* __restrict__ winner, const ushortT* __restrict__ f2b,
                              ushortT* __restrict__ grid) {
    const int total = PSP1*16;
    for (int e = blockIdx.x*256 + threadIdx.x; e < total; e += gridDim.x*256) {
        int pos = e >> 4, ch = e & 15;
        int pz = pos / (P1H*P1W); int rr = pos % (P1H*P1W);
        int py = rr / P1W; int px = rr % P1W;
        unsigned dz = pz-1, dy = py-1, dx = px-1;
        int4 v = {0,0,0,0};
        if (dz < GD && dy < GH && dx < GW) {
            int wn_ = winner[(dz*GH + dy)*GW + dx];
            if (wn_ >= 0) v = *(const int4*)(f2b + (size_t)wn_*C2 + ch*8);
        }
        *(int4*)(grid + ((size_t)pos << 7) + ch*8) = v;
    }
}

// ---------------- conv3d as tap-GEMM (m97 skeleton) -------------------------
// Phase s = one tap (CI=128) or tap x ci-half (CI=256): K=128 GEMM step.
// Double-buffered s_x/s_w staged via global_load_lds; 1 barrier per phase.
// LDS chunks XOR-swizzled (chunk ^= row&7); sources pre-swizzled.
template<int CI, int CO, int TILE_CO, int TILE_SP, int THREADS,
         int PD, int PH, int PW, int DO, int HO, int WO,
         int OPH, int OPW, int NS, int NSLICE, bool ATOMIC>
__global__ __launch_bounds__(THREADS, 2) void conv3d_mfma(
        const ushortT* __restrict__ in_p, const ushortT* __restrict__ wb,
        void* __restrict__ outp, float* __restrict__ sums_out) {
    constexpr int NW      = THREADS/64;
    constexpr int WAVES_M = TILE_CO/32;
    constexpr int WAVES_N = NW/WAVES_M;
    constexpr int FRAG_N  = TILE_SP/(WAVES_N*16);
    constexpr int TILE_Y  = TILE_SP/8;
    constexpr int SPB     = NS/NSLICE;
    constexpr int WCH     = TILE_CO*16;

    __shared__ ushortT s_x[2][TILE_SP*128];
    __shared__ ushortT s_w[2][TILE_CO*128];

    constexpr int nbx = WO/8, nby = HO/TILE_Y;
    int b = blockIdx.x;
    const int bx = b % nbx; b /= nbx;
    const int by = b % nby; b /= nby;
    const int bz = b % DO;  b /= DO;
    const int cob   = b % (CO/TILE_CO);
    const int slice = b / (CO/TILE_CO);
    const int co0 = cob*TILE_CO;
    const int oy0 = by*TILE_Y, ox0 = bx*8;
    const int t = threadIdx.x;
    const int lane = t & 63, wid = t >> 6;
    const int lr = lane & 15, lq = lane >> 4;
    const int wm = wid % WAVES_M, wn = wid / WAVES_M;

    // per-thread input-staging source invariants (chunk -> pre-swizzled addr)
    size_t xpre[4];
    #pragma unroll
    for (int j = 0; j < 4; ++j) {
        int q = t + j*THREADS;
        int n = q >> 4, cp = q & 15;
        int cl = cp ^ (n & 7);
        int oy = n >> 3, ox = n & 7;
        xpre[j] = (size_t)(((2*bz)*PH + (2*oy0 + 2*oy))*PW + (2*ox0 + 2*ox))*CI + cl*8;
    }
    // compute-side row bases
    int aoff[2], axr[2], boff[FRAG_N], bxr[FRAG_N];
    #pragma unroll
    for (int f = 0; f < 2; ++f) {
        int c = wm*32 + f*16 + lr;
        aoff[f] = c*128; axr[f] = c & 7;
    }
    #pragma unroll
    for (int f = 0; f < FRAG_N; ++f) {
        int n = wn*(FRAG_N*16) + f*16 + lr;
        boff[f] = n*128; bxr[f] = n & 7;
    }

    f32x4 acc[2][FRAG_N];
    #pragma unroll
    for (int i = 0; i < 2; ++i)
        #pragma unroll
        for (int j = 0; j < FRAG_N; ++j) acc[i][j] = (f32x4){0.f,0.f,0.f,0.f};

    const int s0 = slice*SPB;

#define STAGE(bufi, s) { \
    const int tap_ = (CI==256) ? ((s)>>1) : (s); \
    const int cib_ = (CI==256) ? (((s)&1)*128) : 0; \
    const int kz_ = tap_/9, ky_ = (tap_/3)%3, kx_ = tap_%3; \
    const ushortT* wsrc_ = wb + ((size_t)(cob*NS + (s)))*(WCH*8); \
    _Pragma("unroll") for (int j = 0; j < 4; ++j) \
        gload16(wsrc_ + (size_t)(t + j*THREADS)*8, &s_w[bufi][(wid*64 + j*THREADS)*8]); \
    const size_t koff_ = (size_t)((kz_*PH + ky_)*PW + kx_)*CI + cib_; \
    _Pragma("unroll") for (int j = 0; j < 4; ++j) \
        gload16(in_p + xpre[j] + koff_, &s_x[bufi][(wid*64 + j*THREADS)*8]); }

#define COMPUTE(bufi) { \
    _Pragma("unroll") for (int ks = 0; ks < 4; ++ks) { \
        int cl_ = ks*4 + lq; \
        bf16x8 a0 = *(const bf16x8*)&s_w[bufi][aoff[0] + ((cl_ ^ axr[0])<<3)]; \
        bf16x8 a1 = *(const bf16x8*)&s_w[bufi][aoff[1] + ((cl_ ^ axr[1])<<3)]; \
        _Pragma("unroll") for (int f = 0; f < FRAG_N; ++f) { \
            bf16x8 bf = *(const bf16x8*)&s_x[bufi][boff[f] + ((cl_ ^ bxr[f])<<3)]; \
            acc[0][f] = __builtin_amdgcn_mfma_f32_16x16x32_bf16(a0, bf, acc[0][f],0,0,0); \
            acc[1][f] = __builtin_amdgcn_mfma_f32_16x16x32_bf16(a1, bf, acc[1][f],0,0,0); } } }

    STAGE(0, s0);
    __syncthreads();
    #pragma unroll
    for (int ph = 0; ph < SPB; ++ph) {
        const int buf = ph & 1;
        if (ph + 1 < SPB) STAGE(buf^1, s0 + ph + 1);
        COMPUTE(buf);
        __syncthreads();
    }
#undef STAGE
#undef COMPUTE

    if constexpr (!ATOMIC) {
        ushortT* out = (ushortT*)outp;   // [pos][CO] padded channels-last
        #pragma unroll
        for (int fm = 0; fm < 2; ++fm)
        #pragma unroll
        for (int fn = 0; fn < FRAG_N; ++fn) {
            int n = wn*(FRAG_N*16) + fn*16 + lr;
            int oy = n >> 3, ox = n & 7;
            int c_ = co0 + wm*32 + fm*16 + lq*4;
            size_t pa = ((size_t)(bz+1)*OPH + (oy0+oy+1))*OPW + (ox0+ox+1);
            ushort4 o;
            o.x = f2bf(acc[fm][fn][0]); o.y = f2bf(acc[fm][fn][1]);
            o.z = f2bf(acc[fm][fn][2]); o.w = f2bf(acc[fm][fn][3]);
            *(ushort4*)(out + pa*CO + c_) = o;
        }
        // fused BN stats (raw fp32 accumulators)
        #pragma unroll
        for (int fm = 0; fm < 2; ++fm) {
            float sv[4], qv[4];
            #pragma unroll
            for (int r = 0; r < 4; ++r) {
                float ssum = 0.f, qsum = 0.f;
                #pragma unroll
                for (int fn = 0; fn < FRAG_N; ++fn) {
                    float a = acc[fm][fn][r]; ssum += a; qsum += a*a;
                }
                #pragma unroll
                for (int m = 1; m < 16; m <<= 1) {
                    ssum += __shfl_xor(ssum, m, 64);
                    qsum += __shfl_xor(qsum, m, 64);
                }
                sv[r] = ssum; qv[r] = qsum;
            }
            if (lr == 0) {
                int c_ = co0 + wm*32 + fm*16 + lq*4;
                #pragma unroll
                for (int r = 0; r < 4; ++r) {
                    atomicAdd(&sums_out[c_+r], sv[r]);
                    atomicAdd(&sums_out[CO + c_+r], qv[r]);
                }
            }
        }
    } else {
        float* out = (float*)outp;       // channel-major fp32 (d_out)
        #pragma unroll
        for (int fm = 0; fm < 2; ++fm)
        #pragma unroll
        for (int fn = 0; fn < FRAG_N; ++fn) {
            int n = wn*(FRAG_N*16) + fn*16 + lr;
            int oy = n >> 3, ox = n & 7;
            int c_ = co0 + wm*32 + fm*16 + lq*4;
            #pragma unroll
            for (int r = 0; r < 4; ++r)
                atomicAdd(&out[((size_t)(c_+r)*DO + bz)*(HO*WO) + (oy0+oy)*WO + ox0+ox],
                          acc[fm][fn][r]);
        }
    }
}

// ---------------- BN apply in place on padded channels-last bf16 ------------
template<int C, int PD, int PH, int PW>
__global__ void bn_apply_pad(ushortT* __restrict__ y, const float* __restrict__ sums,
                             const float* __restrict__ g, const float* __restrict__ be,
                             float invN) {
    constexpr int CH = C/8;
    constexpr int total = PD*PH*PW*CH;
    __shared__ float s_sc[C], s_sh[C];
    for (int c = threadIdx.x; c < C; c += 256) {
        float mean = sums[c]*invN;
        float var  = sums[C+c]*invN - mean*mean;
        float sc = g[c]*rsqrtf(var + EPSBN);
        s_sc[c] = sc; s_sh[c] = be[c] - mean*sc;
    }
    __syncthreads();
    for (int e = blockIdx.x*256 + threadIdx.x; e < total; e += gridDim.x*256) {
        int pos = e / CH;
        int c0 = (e % CH)*8;
        int pz = pos / (PH*PW); int rr = pos % (PH*PW);
        int py = rr / PW; int px = rr % PW;
        if ((unsigned)(pz-1) >= (unsigned)(PD-2) || (unsigned)(py-1) >= (unsigned)(PH-2) ||
            (unsigned)(px-1) >= (unsigned)(PW-2)) continue;   // pads stay zero
        ushortT* p = y + (size_t)pos*C + c0;
        ushort4 a = *(ushort4*)p, b4 = *(ushort4*)(p+4);
        ushort4 o1, o2;
        o1.x = f2bf(fmaxf(0.f, bf2f(a.x)*s_sc[c0+0]+s_sh[c0+0]));
        o1.y = f2bf(fmaxf(0.f, bf2f(a.y)*s_sc[c0+1]+s_sh[c0+1]));
        o1.z = f2bf(fmaxf(0.f, bf2f(a.z)*s_sc[c0+2]+s_sh[c0+2]));
        o1.w = f2bf(fmaxf(0.f, bf2f(a.w)*s_sc[c0+3]+s_sh[c0+3]));
        o2.x = f2bf(fmaxf(0.f, bf2f(b4.x)*s_sc[c0+4]+s_sh[c0+4]));
        o2.y = f2bf(fmaxf(0.f, bf2f(b4.y)*s_sc[c0+5]+s_sh[c0+5]));
        o2.z = f2bf(fmaxf(0.f, bf2f(b4.z)*s_sc[c0+6]+s_sh[c0+6]));
        o2.w = f2bf(fmaxf(0.f, bf2f(b4.w)*s_sc[c0+7]+s_sh[c0+7]));
        *(ushort4*)p     = o1;
        *(ushort4*)(p+4) = o2;
    }
}

// ---------------- BN for channel-major fp32 (final output) -----------------
template<int SPL>
__global__ void bn_stats_cmajor(const float* __restrict__ y, const float* __restrict__ g,
                                const float* __restrict__ be, float* __restrict__ ss, int C) {
    __shared__ float s_red[2][256];
    int c = blockIdx.x;
    const float* p = y + (size_t)c*SPL;
    float sum = 0.f, sq = 0.f;
    for (int i = threadIdx.x; i < SPL; i += 256) { float v = p[i]; sum += v; sq += v*v; }
    s_red[0][threadIdx.x] = sum; s_red[1][threadIdx.x] = sq;
    __syncthreads();
    for (int s = 128; s > 0; s >>= 1) {
        if (threadIdx.x < s) {
            s_red[0][threadIdx.x] += s_red[0][threadIdx.x+s];
            s_red[1][threadIdx.x] += s_red[1][threadIdx.x+s];
        }
        __syncthreads();
    }
    if (threadIdx.x == 0) {
        float invN = 1.f/(float)SPL;
        float mean = s_red[0][0]*invN;
        float var  = s_red[1][0]*invN - mean*mean;
        float sc = g[c]*rsqrtf(var + EPSBN);
        ss[c] = sc; ss[C+c] = be[c] - mean*sc;
    }
}

template<int LOGSPL>
__global__ void bn_apply_cmajor(float* __restrict__ y, const float* __restrict__ ss,
                                int C, int total) {
    for (int i = blockIdx.x*blockDim.x + threadIdx.x; i < total; i += gridDim.x*blockDim.x) {
        int c = i >> LOGSPL;
        y[i] = fmaxf(0.f, y[i]*ss[c] + ss[C+c]);
    }
}

// ---------------- host launcher --------------------------------------------
extern "C" void kernel_launch(void* const* d_in, const int* in_sizes, int n_in,
                              void* d_out, int out_size, void* d_ws, size_t ws_size,
                              hipStream_t stream) {
    const float* x      = (const float*)d_in[0];
    const int*   coords = (const int*)  d_in[1];
    const float* w1  = (const float*)d_in[5];
    const float* g1  = (const float*)d_in[7];
    const float* be1 = (const float*)d_in[8];
    const float* w2  = (const float*)d_in[9];
    const float* g2  = (const float*)d_in[11];
    const float* be2 = (const float*)d_in[12];
    const float* cw1 = (const float*)d_in[13];
    const float* cg1 = (const float*)d_in[15];
    const float* cbe1= (const float*)d_in[16];
    const float* cw2 = (const float*)d_in[17];
    const float* cg2 = (const float*)d_in[19];
    const float* cbe2= (const float*)d_in[20];
    const float* cw3 = (const float*)d_in[21];
    const float* cg3 = (const float*)d_in[23];
    const float* cbe3= (const float*)d_in[24];
    float* out = (float*)d_out;

    // ---- workspace layout ----
    float*   ws     = (float*)d_ws;
    float*   stats  = ws;                                    // 4096 f32
    int*     winner = (int*)(ws + 4096);                     // SP
    float*   f1     = (float*)(winner + SP);                 // 12000*64
    float*   y2     = f1 + (size_t)NVOX*C1;                  // 12000*128
    ushortT* f2b    = (ushortT*)(y2 + (size_t)NVOX*C2);      // 12000*128
    ushortT* grid   = f2b + (size_t)NVOX*C2;                 // PSP1*128
    ushortT* c1o    = grid + (size_t)PSP1*128;               // PSP2*128
    ushortT* c2o    = c1o + (size_t)PSP2*128;                // PSP3*256
    ushortT* wb1    = c2o + (size_t)PSP3*256;                // 442368
    ushortT* wb2    = wb1 + 442368;                          // 884736
    ushortT* wb3    = wb2 + 884736;                          // 1769472

    float* s1sum = stats;          // 128
    float* s2sum = stats + 128;    // 256
    float* c1sum = stats + 384;    // 256
    float* c2sum = stats + 640;    // 512
    float* ss3   = stats + 1152;   // 512

    hipMemsetAsync(stats, 0, 4096*sizeof(float), stream);
    hipMemsetAsync(winner, 0xFF, SP*sizeof(int), stream);
    hipMemsetAsync(c1o, 0, (size_t)PSP2*128*2, stream);
    hipMemsetAsync(c2o, 0, (size_t)PSP3*256*2, stream);
    hipMemsetAsync(d_out, 0, (size_t)out_size*sizeof(float), stream);

    prep<<<2031, 256, 0, stream>>>(x, w1, s1sum, cw1, cw2, cw3, wb1, wb2, wb3,
                                   coords, winner);
    vfe1_apply<<<NVOX, 64, 0, stream>>>(x, w1, s1sum, g1, be1, f1);
    vfe2_linear<<<NVOX/16, 128, 0, stream>>>(f1, w2, y2, s2sum);
    vfe2_apply_bf16<<<NVOX*C2/4/256, 256, 0, stream>>>(y2, s2sum, g2, be2, f2b);
    build_grid_cl<<<4096, 256, 0, stream>>>(winner, f2b, grid);

    // conv1: 128->128, grid(18,130,130) -> c1o(10,66,66); big tile 128x128, 512 thr
    conv3d_mfma<128,128, 128,128,512, P1D,P1H,P1W, 8,64,64, P2H,P2W, 27,1,false>
        <<<8*4*8, 512, 0, stream>>>(grid, wb1, c1o, c1sum);
    bn_apply_pad<128, P2D,P2H,P2W><<<1024, 256, 0, stream>>>(c1o, c1sum, cg1, cbe1,
                                                             1.f/32768.f);
    // conv2: 128->256, c1o -> c2o(6,34,34); 64x64 tile
    conv3d_mfma<128,256, 64,64,256, P2D,P2H,P2W, 4,32,32, P3H,P3W, 27,1,false>
        <<<4*4*4*4, 256, 0, stream>>>(c1o, wb2, c2o, c2sum);
    bn_apply_pad<256, P3D,P3H,P3W><<<512, 256, 0, stream>>>(c2o, c2sum, cg2, cbe2,
                                                            1.f/4096.f);
    // conv3: 256->256, c2o -> d_out fp32 cmajor; 54 phases, 6 slices, atomic
    conv3d_mfma<256,256, 64,64,256, P3D,P3H,P3W, 2,16,16, 1,1, 54,6,true>
        <<<2*2*2*4*6, 256, 0, stream>>>(c2o, wb3, (void*)out, nullptr);

    bn_stats_cmajor<2*16*16><<<256, 256, 0, stream>>>(out, cg3, cbe3, ss3, 256);
    bn_apply_cmajor<9><<<512, 256, 0, stream>>>(out, ss3, 256, 131072);
}